// Round 5
// baseline (828.594 us; speedup 1.0000x reference)
//
#include <hip/hip_runtime.h>
#include <math.h>

#define GK 602
#define GH 128
#define GC 41
#define GCP 48     // padded class count for layer-2 aggregate
#define KPAD 608   // 19 k-tiles of 32
#define NKT 19

typedef __bf16 bf16x8 __attribute__((ext_vector_type(8)));
typedef float f32x16 __attribute__((ext_vector_type(16)));

__device__ __forceinline__ unsigned short f2bf(float f) {
    __bf16 b = (__bf16)f;
    return __builtin_bit_cast(unsigned short, b);
}
__device__ __forceinline__ float bf2f(unsigned short u) {
    return __uint_as_float((unsigned int)u << 16);
}
__device__ __forceinline__ float bflo(unsigned int u) { return __uint_as_float(u << 16); }
__device__ __forceinline__ float bfhi(unsigned int u) { return __uint_as_float(u & 0xffff0000u); }

// ---------------- CSR build ----------------

__global__ void k_hist(const int* __restrict__ dst, int* __restrict__ counts, int E) {
    int e = blockIdx.x * 256 + threadIdx.x;
    if (e < E) atomicAdd(&counts[dst[e]], 1);
}

// exclusive scan of counts -> row_ptr, 1024 elems/block, shuffle-based
__global__ void k_scan_a(const int* __restrict__ counts, int* __restrict__ row_ptr,
                         int* __restrict__ bsum, int n) {
    __shared__ int wsum[4];
    int t = threadIdx.x;
    int lane = t & 63;
    int wv = t >> 6;
    int base = blockIdx.x * 1024 + t * 4;
    int v[4];
    int s = 0;
#pragma unroll
    for (int j = 0; j < 4; ++j) {
        int idx = base + j;
        v[j] = (idx < n) ? counts[idx] : 0;
        s += v[j];
    }
    int incl = s;
#pragma unroll
    for (int o = 1; o < 64; o <<= 1) {
        int x = __shfl_up(incl, o);
        if (lane >= o) incl += x;
    }
    if (lane == 63) wsum[wv] = incl;
    __syncthreads();
    int woff = 0;
#pragma unroll
    for (int i = 0; i < 3; ++i) woff += (i < wv) ? wsum[i] : 0;
    if (t == 255) bsum[blockIdx.x] = woff + incl;
    int off = woff + incl - s;
#pragma unroll
    for (int j = 0; j < 4; ++j) {
        int idx = base + j;
        if (idx < n) row_ptr[idx] = off;
        off += v[j];
    }
}

// single-block exclusive scan of bsum (nb <= 256)
__global__ void k_scan_b(int* __restrict__ bsum, int nb) {
    __shared__ int sh[256];
    int t = threadIdx.x;
    int v = (t < nb) ? bsum[t] : 0;
    sh[t] = v;
    __syncthreads();
    for (int o = 1; o < 256; o <<= 1) {
        int x = (t >= o) ? sh[t - o] : 0;
        __syncthreads();
        sh[t] += x;
        __syncthreads();
    }
    if (t < nb) bsum[t] = sh[t] - v;
}

// finalize row_ptr, init cursor, compute dinv (fused)
__global__ void k_scan_c(int* __restrict__ row_ptr, const int* __restrict__ bsum,
                         const int* __restrict__ counts, float* __restrict__ dinv,
                         int* __restrict__ cursor, int n, int E) {
    int i = blockIdx.x * 256 + threadIdx.x;
    if (i < n) {
        int rp = row_ptr[i] + bsum[i >> 10];
        row_ptr[i] = rp;
        cursor[i] = rp;
        dinv[i] = rsqrtf((float)(counts[i] + 1));  // +1 self-loop
    }
    if (i == 0) row_ptr[n] = E;
}

// fill per-edge meta: {src, norm = dinv[src]*dinv[dst]} grouped by dst (CSR order)
__global__ void k_fill(const int* __restrict__ src, const int* __restrict__ dst,
                       const float* __restrict__ dinv,
                       int* __restrict__ cursor, int2* __restrict__ meta, int E) {
    int e = blockIdx.x * 256 + threadIdx.x;
    if (e < E) {
        int s = src[e];
        int d = dst[e];
        int p = atomicAdd(&cursor[d], 1);
        float w = dinv[s] * dinv[d];
        meta[p] = make_int2(s, __float_as_int(w));
    }
}

// ---------------- W1 -> bf16 transposed+padded: W1T[n][k], n<128, k<608 ----------------

__global__ void k_prepW1(const float* __restrict__ W1, unsigned short* __restrict__ W1T) {
    int i = blockIdx.x * 256 + threadIdx.x;
    if (i >= GH * KPAD) return;
    int n = i / KPAD;
    int k = i - n * KPAD;
    float v = (k < GK) ? W1[(size_t)k * GH + n] : 0.f;
    W1T[i] = f2bf(v);
}

// ---------------- GEMM1 via MFMA bf16: X(M x 602) @ W1 -> Y bf16 (M x 128) ----------------
// NO LDS, NO BARRIERS: each wave owns 32 rows; A triple-buffered in registers
// from global; B fragments loaded directly from global (152 KB W1T is L1/L2-hot
// since every block reads the identical stream).

struct AF { float4 v0, v1, v2, v3; };

__device__ __forceinline__ AF loadA(const float* __restrict__ xr, int kb, bool tail) {
    AF r;
    if (!tail) {
        r.v0 = *(const float4*)(xr + kb);
        r.v1 = *(const float4*)(xr + kb + 4);
        r.v2 = *(const float4*)(xr + kb + 16);
        r.v3 = *(const float4*)(xr + kb + 20);
    } else {
        float tv[8], tw[8];
#pragma unroll
        for (int j = 0; j < 8; ++j) {
            int k0_ = kb + j;
            int k1_ = kb + 16 + j;
            tv[j] = (k0_ < GK) ? xr[k0_] : 0.f;
            tw[j] = (k1_ < GK) ? xr[k1_] : 0.f;
        }
        r.v0 = make_float4(tv[0], tv[1], tv[2], tv[3]);
        r.v1 = make_float4(tv[4], tv[5], tv[6], tv[7]);
        r.v2 = make_float4(tw[0], tw[1], tw[2], tw[3]);
        r.v3 = make_float4(tw[4], tw[5], tw[6], tw[7]);
    }
    return r;
}

__device__ __forceinline__ bf16x8 cvt8(float4 a, float4 b) {
    bf16x8 r;
    r[0] = (__bf16)a.x; r[1] = (__bf16)a.y; r[2] = (__bf16)a.z; r[3] = (__bf16)a.w;
    r[4] = (__bf16)b.x; r[5] = (__bf16)b.y; r[6] = (__bf16)b.z; r[7] = (__bf16)b.w;
    return r;
}

__global__ __launch_bounds__(256) void k_gemm1_mfma(const float* __restrict__ X,
                                                    const unsigned short* __restrict__ W1T,
                                                    unsigned short* __restrict__ Y, int M) {
    int tid = threadIdx.x;
    int lane = tid & 63;
    int w = tid >> 6;
    int row0 = blockIdx.x * 128 + 32 * w;    // this wave's 32-row base
    int grow_base = row0 + (lane & 31);
    int arow = (grow_base < M) ? grow_base : (M - 1);  // clamp OOB rows (not stored)
    const float* xr = X + (size_t)arow * GK;
    int kh = (lane >> 5) * 8;                // 0 or 8
    int bn = lane & 31;

    f32x16 acc[4];
#pragma unroll
    for (int c = 0; c < 4; ++c)
#pragma unroll
        for (int i = 0; i < 16; ++i) acc[c][i] = 0.f;

    AF a0 = loadA(xr, kh, false);
    AF a1 = loadA(xr, kh + 32, false);

    for (int it = 0; it < NKT; ++it) {
        AF a2;
        if (it + 2 < NKT) a2 = loadA(xr, kh + 32 * (it + 2), (it + 2) == (NKT - 1));
        bf16x8 af0 = cvt8(a0.v0, a0.v1);
        bf16x8 af1 = cvt8(a0.v2, a0.v3);
        const unsigned short* bbase = W1T + 32 * it + kh;
#pragma unroll
        for (int c = 0; c < 4; ++c) {
            bf16x8 b0 = *(const bf16x8*)&bbase[(size_t)(32 * c + bn) * KPAD];
            acc[c] = __builtin_amdgcn_mfma_f32_32x32x16_bf16(af0, b0, acc[c], 0, 0, 0);
        }
#pragma unroll
        for (int c = 0; c < 4; ++c) {
            bf16x8 b1 = *(const bf16x8*)&bbase[(size_t)(32 * c + bn) * KPAD + 16];
            acc[c] = __builtin_amdgcn_mfma_f32_32x32x16_bf16(af1, b1, acc[c], 0, 0, 0);
        }
        a0 = a1;
        a1 = a2;
    }
    // epilogue: C/D layout col=lane&31, row=(reg&3)+8*(reg>>2)+4*(lane>>5)
#pragma unroll
    for (int c = 0; c < 4; ++c) {
#pragma unroll
        for (int reg = 0; reg < 16; ++reg) {
            int rrow = (reg & 3) + 8 * (reg >> 2) + 4 * (lane >> 5);
            int grow = row0 + rrow;
            int gcol = 32 * c + (lane & 31);
            if (grow < M) Y[(size_t)grow * GH + gcol] = f2bf(acc[c][reg]);
        }
    }
}

// ---------------- layer-1 aggregate: 128-wide bf16 gather, unroll-16 MLP ----------------

__global__ __launch_bounds__(256) void k_agg1(const unsigned int* __restrict__ H,
                                              unsigned int* __restrict__ O,
                                              const int* __restrict__ row_ptr,
                                              const int2* __restrict__ meta,
                                              const float* __restrict__ dinv,
                                              const float* __restrict__ bias, int n) {
    int wv = threadIdx.x >> 6;
    int lane = threadIdx.x & 63;
    int d = blockIdx.x * 4 + wv;
    if (d >= n) return;
    float dd = dinv[d];
    int beg = row_ptr[d], end = row_ptr[d + 1];
    unsigned int v = H[(size_t)d * 64 + lane];
    float sw = dd * dd;
    float a0 = sw * bflo(v);
    float a1 = sw * bfhi(v);
    int e = beg;
    for (; e + 16 <= end; e += 16) {
        int2 m[16];
        unsigned int u[16];
#pragma unroll
        for (int j = 0; j < 16; ++j) m[j] = meta[e + j];
#pragma unroll
        for (int j = 0; j < 16; ++j) u[j] = H[(size_t)m[j].x * 64 + lane];
#pragma unroll
        for (int j = 0; j < 16; ++j) {
            float wj = __int_as_float(m[j].y);
            a0 = fmaf(wj, bflo(u[j]), a0);
            a1 = fmaf(wj, bfhi(u[j]), a1);
        }
    }
    if (e + 8 <= end) {
        int2 m[8];
        unsigned int u[8];
#pragma unroll
        for (int j = 0; j < 8; ++j) m[j] = meta[e + j];
#pragma unroll
        for (int j = 0; j < 8; ++j) u[j] = H[(size_t)m[j].x * 64 + lane];
#pragma unroll
        for (int j = 0; j < 8; ++j) {
            float wj = __int_as_float(m[j].y);
            a0 = fmaf(wj, bflo(u[j]), a0);
            a1 = fmaf(wj, bfhi(u[j]), a1);
        }
        e += 8;
    }
    if (e + 4 <= end) {
        int2 m[4];
        unsigned int u[4];
#pragma unroll
        for (int j = 0; j < 4; ++j) m[j] = meta[e + j];
#pragma unroll
        for (int j = 0; j < 4; ++j) u[j] = H[(size_t)m[j].x * 64 + lane];
#pragma unroll
        for (int j = 0; j < 4; ++j) {
            float wj = __int_as_float(m[j].y);
            a0 = fmaf(wj, bflo(u[j]), a0);
            a1 = fmaf(wj, bfhi(u[j]), a1);
        }
        e += 4;
    }
    for (; e < end; ++e) {
        int2 m = meta[e];
        unsigned int u = H[(size_t)m.x * 64 + lane];
        float wj = __int_as_float(m.y);
        a0 = fmaf(wj, bflo(u), a0);
        a1 = fmaf(wj, bfhi(u), a1);
    }
    a0 = fmaxf(a0 + bias[2 * lane], 0.f);
    a1 = fmaxf(a1 + bias[2 * lane + 1], 0.f);
    O[(size_t)d * 64 + lane] = (unsigned int)f2bf(a0) | ((unsigned int)f2bf(a1) << 16);
}

// ---------------- layer-2 transform first: G = relu(H1) @ W2, bf16 out, padded to 48 ----------------

__global__ __launch_bounds__(256) void k_gemm2t(const unsigned int* __restrict__ Hb,
                                                const float* __restrict__ W2,
                                                unsigned short* __restrict__ G, int n) {
    __shared__ float ws[128][GCP];
    for (int i = threadIdx.x; i < 128 * GCP; i += 256) {
        int k = i / GCP;
        int c = i - k * GCP;
        ws[k][c] = (c < GC) ? W2[k * GC + c] : 0.f;
    }
    __syncthreads();
    int r0 = blockIdx.x * 512 + threadIdx.x;
    int r1 = r0 + 256;
    bool v0 = r0 < n, v1 = r1 < n;
    float acc0[GCP], acc1[GCP];
#pragma unroll
    for (int c = 0; c < GCP; ++c) { acc0[c] = 0.f; acc1[c] = 0.f; }
    const uint2* h0 = (const uint2*)(Hb + (size_t)(v0 ? r0 : 0) * 64);
    const uint2* h1 = (const uint2*)(Hb + (size_t)(v1 ? r1 : 0) * 64);
    for (int q = 0; q < 32; ++q) {
        uint2 ua = h0[q];
        uint2 ub = h1[q];
        float va[4] = {bflo(ua.x), bfhi(ua.x), bflo(ua.y), bfhi(ua.y)};
        float vb[4] = {bflo(ub.x), bfhi(ub.x), bflo(ub.y), bfhi(ub.y)};
#pragma unroll
        for (int j = 0; j < 4; ++j) {
            int k = 4 * q + j;
#pragma unroll
            for (int cq = 0; cq < GCP / 4; ++cq) {
                float4 wv = *(const float4*)&ws[k][4 * cq];
                acc0[4 * cq + 0] = fmaf(va[j], wv.x, acc0[4 * cq + 0]);
                acc0[4 * cq + 1] = fmaf(va[j], wv.y, acc0[4 * cq + 1]);
                acc0[4 * cq + 2] = fmaf(va[j], wv.z, acc0[4 * cq + 2]);
                acc0[4 * cq + 3] = fmaf(va[j], wv.w, acc0[4 * cq + 3]);
                acc1[4 * cq + 0] = fmaf(vb[j], wv.x, acc1[4 * cq + 0]);
                acc1[4 * cq + 1] = fmaf(vb[j], wv.y, acc1[4 * cq + 1]);
                acc1[4 * cq + 2] = fmaf(vb[j], wv.z, acc1[4 * cq + 2]);
                acc1[4 * cq + 3] = fmaf(vb[j], wv.w, acc1[4 * cq + 3]);
            }
        }
    }
    if (v0) {
#pragma unroll
        for (int c = 0; c < GCP; ++c) G[(size_t)r0 * GCP + c] = f2bf(acc0[c]);
    }
    if (v1) {
#pragma unroll
        for (int c = 0; c < GCP; ++c) G[(size_t)r1 * GCP + c] = f2bf(acc1[c]);
    }
}

// ---------------- layer-2 aggregate at width 48 + bias + log_softmax, write d_out ----------------

__global__ __launch_bounds__(256) void k_agg2(const unsigned short* __restrict__ G,
                                              float* __restrict__ out,
                                              const int* __restrict__ row_ptr,
                                              const int2* __restrict__ meta,
                                              const float* __restrict__ dinv,
                                              const float* __restrict__ b2, int n) {
    int wv = threadIdx.x >> 6;
    int lane = threadIdx.x & 63;
    int gl = (lane < GCP) ? lane : (GCP - 1);
    int d = blockIdx.x * 4 + wv;
    if (d >= n) return;
    float dd = dinv[d];
    int beg = row_ptr[d], end = row_ptr[d + 1];
    float a = dd * dd * bf2f(G[(size_t)d * GCP + gl]);
    int e = beg;
    for (; e + 16 <= end; e += 16) {
        int2 m[16];
        unsigned short u[16];
#pragma unroll
        for (int j = 0; j < 16; ++j) m[j] = meta[e + j];
#pragma unroll
        for (int j = 0; j < 16; ++j) u[j] = G[(size_t)m[j].x * GCP + gl];
#pragma unroll
        for (int j = 0; j < 16; ++j) a = fmaf(__int_as_float(m[j].y), bf2f(u[j]), a);
    }
    if (e + 8 <= end) {
        int2 m[8];
        unsigned short u[8];
#pragma unroll
        for (int j = 0; j < 8; ++j) m[j] = meta[e + j];
#pragma unroll
        for (int j = 0; j < 8; ++j) u[j] = G[(size_t)m[j].x * GCP + gl];
#pragma unroll
        for (int j = 0; j < 8; ++j) a = fmaf(__int_as_float(m[j].y), bf2f(u[j]), a);
        e += 8;
    }
    if (e + 4 <= end) {
        int2 m[4];
        unsigned short u[4];
#pragma unroll
        for (int j = 0; j < 4; ++j) m[j] = meta[e + j];
#pragma unroll
        for (int j = 0; j < 4; ++j) u[j] = G[(size_t)m[j].x * GCP + gl];
#pragma unroll
        for (int j = 0; j < 4; ++j) a = fmaf(__int_as_float(m[j].y), bf2f(u[j]), a);
        e += 4;
    }
    for (; e < end; ++e) {
        int2 m = meta[e];
        a = fmaf(__int_as_float(m.y), bf2f(G[(size_t)m.x * GCP + gl]), a);
    }
    float logit = (lane < GC) ? (a + b2[lane]) : -INFINITY;
    float mx = logit;
#pragma unroll
    for (int off = 32; off; off >>= 1) mx = fmaxf(mx, __shfl_xor(mx, off));
    float ex = (lane < GC) ? __expf(logit - mx) : 0.f;
    float sm = ex;
#pragma unroll
    for (int off = 32; off; off >>= 1) sm += __shfl_xor(sm, off);
    if (lane < GC) out[(size_t)d * GC + lane] = logit - mx - __logf(sm);
}

// ---------------- launch ----------------

static inline size_t alignup256(size_t x) { return (x + 255) & ~(size_t)255; }

extern "C" void kernel_launch(void* const* d_in, const int* in_sizes, int n_in,
                              void* d_out, int out_size, void* d_ws, size_t ws_size,
                              hipStream_t stream) {
    const float* x  = (const float*)d_in[0];
    const int*   ei = (const int*)d_in[1];
    const float* W1 = (const float*)d_in[2];
    const float* b1 = (const float*)d_in[3];
    const float* W2 = (const float*)d_in[4];
    const float* b2 = (const float*)d_in[5];
    float* out = (float*)d_out;

    const int n = in_sizes[0] / GK;   // 100000
    const int E = in_sizes[1] / 2;    // 1600000
    const int* src = ei;
    const int* dst = ei + E;

    char* w = (char*)d_ws;
    char* p;
    p = w; w += alignup256((size_t)n * 4);            float* dinv  = (float*)p;
    p = w; w += alignup256((size_t)n * 4);            int* counts  = (int*)p;
    p = w; w += alignup256((size_t)n * 4);            int* cursor  = (int*)p;
    p = w; w += alignup256((size_t)(n + 1) * 4);      int* row_ptr = (int*)p;
    p = w; w += alignup256(1024 * 4);                 int* bsum    = (int*)p;
    p = w; w += alignup256((size_t)E * 8);            int2* meta   = (int2*)p;
    p = w; w += alignup256((size_t)GH * KPAD * 2);    unsigned short* W1T = (unsigned short*)p;
    p = w; w += alignup256((size_t)n * GH * 2);       unsigned short* bufA = (unsigned short*)p; // bf16 H1
    p = w; w += alignup256((size_t)n * GH * 2);       unsigned short* bufB = (unsigned short*)p; // bf16 relu(agg1)
    p = w; w += alignup256((size_t)n * GCP * 2);      unsigned short* G    = (unsigned short*)p; // bf16 H1relu@W2

    hipMemsetAsync(counts, 0, (size_t)n * 4, stream);

    int gE = (E + 255) / 256;
    int gN = (n + 255) / 256;
    int nb = (n + 1023) / 1024;

    k_hist<<<gE, 256, 0, stream>>>(dst, counts, E);
    k_scan_a<<<nb, 256, 0, stream>>>(counts, row_ptr, bsum, n);
    k_scan_b<<<1, 256, 0, stream>>>(bsum, nb);
    k_scan_c<<<gN, 256, 0, stream>>>(row_ptr, bsum, counts, dinv, cursor, n, E);
    k_fill<<<gE, 256, 0, stream>>>(src, dst, dinv, cursor, meta, E);

    k_prepW1<<<(GH * KPAD + 255) / 256, 256, 0, stream>>>(W1, W1T);
    k_gemm1_mfma<<<(n + 127) / 128, 256, 0, stream>>>(x, W1T, bufA, n);
    k_agg1<<<(n + 3) / 4, 256, 0, stream>>>((const unsigned int*)bufA, (unsigned int*)bufB,
                                            row_ptr, meta, dinv, b1, n);
    k_gemm2t<<<(n + 511) / 512, 256, 0, stream>>>((const unsigned int*)bufB, W2, G, n);
    k_agg2<<<(n + 3) / 4, 256, 0, stream>>>(G, out, row_ptr, meta, dinv, b2, n);
}

// Round 6
// 719.360 us; speedup vs baseline: 1.1518x; 1.1518x over previous
//
#include <hip/hip_runtime.h>
#include <math.h>

#define GK 602
#define GH 128
#define GC 41
#define GCP 48     // padded class count for layer-2 aggregate
#define KPAD 608   // 19 k-tiles of 32
#define NKT 19
#define GS 40      // LDS row stride in bf16 elems (80 B, 16B-aligned)

typedef __bf16 bf16x8 __attribute__((ext_vector_type(8)));
typedef float f32x16 __attribute__((ext_vector_type(16)));

__device__ __forceinline__ unsigned short f2bf(float f) {
    __bf16 b = (__bf16)f;
    return __builtin_bit_cast(unsigned short, b);
}
__device__ __forceinline__ float bf2f(unsigned short u) {
    return __uint_as_float((unsigned int)u << 16);
}
__device__ __forceinline__ float bflo(unsigned int u) { return __uint_as_float(u << 16); }
__device__ __forceinline__ float bfhi(unsigned int u) { return __uint_as_float(u & 0xffff0000u); }

// ---------------- CSR build ----------------

__global__ void k_hist(const int* __restrict__ dst, int* __restrict__ counts, int E) {
    int e = blockIdx.x * 256 + threadIdx.x;
    if (e < E) atomicAdd(&counts[dst[e]], 1);
}

// exclusive scan of counts -> row_ptr, 1024 elems/block, shuffle-based
__global__ void k_scan_a(const int* __restrict__ counts, int* __restrict__ row_ptr,
                         int* __restrict__ bsum, int n) {
    __shared__ int wsum[4];
    int t = threadIdx.x;
    int lane = t & 63;
    int wv = t >> 6;
    int base = blockIdx.x * 1024 + t * 4;
    int v[4];
    int s = 0;
#pragma unroll
    for (int j = 0; j < 4; ++j) {
        int idx = base + j;
        v[j] = (idx < n) ? counts[idx] : 0;
        s += v[j];
    }
    int incl = s;
#pragma unroll
    for (int o = 1; o < 64; o <<= 1) {
        int x = __shfl_up(incl, o);
        if (lane >= o) incl += x;
    }
    if (lane == 63) wsum[wv] = incl;
    __syncthreads();
    int woff = 0;
#pragma unroll
    for (int i = 0; i < 3; ++i) woff += (i < wv) ? wsum[i] : 0;
    if (t == 255) bsum[blockIdx.x] = woff + incl;
    int off = woff + incl - s;
#pragma unroll
    for (int j = 0; j < 4; ++j) {
        int idx = base + j;
        if (idx < n) row_ptr[idx] = off;
        off += v[j];
    }
}

// single-block exclusive scan of bsum (nb <= 256)
__global__ void k_scan_b(int* __restrict__ bsum, int nb) {
    __shared__ int sh[256];
    int t = threadIdx.x;
    int v = (t < nb) ? bsum[t] : 0;
    sh[t] = v;
    __syncthreads();
    for (int o = 1; o < 256; o <<= 1) {
        int x = (t >= o) ? sh[t - o] : 0;
        __syncthreads();
        sh[t] += x;
        __syncthreads();
    }
    if (t < nb) bsum[t] = sh[t] - v;
}

// finalize row_ptr, init cursor, compute dinv (fused)
__global__ void k_scan_c(int* __restrict__ row_ptr, const int* __restrict__ bsum,
                         const int* __restrict__ counts, float* __restrict__ dinv,
                         int* __restrict__ cursor, int n, int E) {
    int i = blockIdx.x * 256 + threadIdx.x;
    if (i < n) {
        int rp = row_ptr[i] + bsum[i >> 10];
        row_ptr[i] = rp;
        cursor[i] = rp;
        dinv[i] = rsqrtf((float)(counts[i] + 1));  // +1 self-loop
    }
    if (i == 0) row_ptr[n] = E;
}

// fill per-edge meta: {src, norm = dinv[src]*dinv[dst]} grouped by dst (CSR order)
__global__ void k_fill(const int* __restrict__ src, const int* __restrict__ dst,
                       const float* __restrict__ dinv,
                       int* __restrict__ cursor, int2* __restrict__ meta, int E) {
    int e = blockIdx.x * 256 + threadIdx.x;
    if (e < E) {
        int s = src[e];
        int d = dst[e];
        int p = atomicAdd(&cursor[d], 1);
        float w = dinv[s] * dinv[d];
        meta[p] = make_int2(s, __float_as_int(w));
    }
}

// ---------------- W1 -> bf16 transposed+padded: W1T[n][k], n<128, k<608 ----------------

__global__ void k_prepW1(const float* __restrict__ W1, unsigned short* __restrict__ W1T) {
    int i = blockIdx.x * 256 + threadIdx.x;
    if (i >= GH * KPAD) return;
    int n = i / KPAD;
    int k = i - n * KPAD;
    float v = (k < GK) ? W1[(size_t)k * GH + n] : 0.f;
    W1T[i] = f2bf(v);
}

// ---------------- GEMM1 via MFMA bf16: X(M x 602) @ W1 -> Y bf16 (M x 128) ----------------
// 64 rows/block (grid 1563 -> ~6 blocks/CU, ~24 waves/CU). Wave w: rows (w&1)*32,
// cols (w>>1)*64. B (W1T) LDS double-buffered (coalesced staging, 1 barrier/iter);
// A per-lane direct from global, depth-2 register prefetch.

struct AF { float4 v0, v1, v2, v3; };

__device__ __forceinline__ AF loadA(const float* __restrict__ xr, int kb, bool tail) {
    AF r;
    if (!tail) {
        r.v0 = *(const float4*)(xr + kb);
        r.v1 = *(const float4*)(xr + kb + 4);
        r.v2 = *(const float4*)(xr + kb + 16);
        r.v3 = *(const float4*)(xr + kb + 20);
    } else {
        float tv[8], tw[8];
#pragma unroll
        for (int j = 0; j < 8; ++j) {
            int k0_ = kb + j;
            int k1_ = kb + 16 + j;
            tv[j] = (k0_ < GK) ? xr[k0_] : 0.f;
            tw[j] = (k1_ < GK) ? xr[k1_] : 0.f;
        }
        r.v0 = make_float4(tv[0], tv[1], tv[2], tv[3]);
        r.v1 = make_float4(tv[4], tv[5], tv[6], tv[7]);
        r.v2 = make_float4(tw[0], tw[1], tw[2], tw[3]);
        r.v3 = make_float4(tw[4], tw[5], tw[6], tw[7]);
    }
    return r;
}

__device__ __forceinline__ bf16x8 cvt8(float4 a, float4 b) {
    bf16x8 r;
    r[0] = (__bf16)a.x; r[1] = (__bf16)a.y; r[2] = (__bf16)a.z; r[3] = (__bf16)a.w;
    r[4] = (__bf16)b.x; r[5] = (__bf16)b.y; r[6] = (__bf16)b.z; r[7] = (__bf16)b.w;
    return r;
}

__device__ __forceinline__ void stageB(const unsigned short* __restrict__ W1T,
                                       __bf16* __restrict__ Bsb, int tid, int k0) {
#pragma unroll
    for (int s = 0; s < 2; ++s) {
        int slot = tid + 256 * s;
        int n = slot >> 2;
        int j = slot & 3;
        uint4 v = *(const uint4*)&W1T[(size_t)n * KPAD + k0 + 8 * j];
        *(uint4*)&Bsb[n * GS + 8 * j] = v;
    }
}

__global__ __launch_bounds__(256) void k_gemm1_mfma(const float* __restrict__ X,
                                                    const unsigned short* __restrict__ W1T,
                                                    unsigned short* __restrict__ Y, int M) {
    __shared__ __bf16 Bs[2][128 * GS];
    int tid = threadIdx.x;
    int lane = tid & 63;
    int w = tid >> 6;
    int rowBase = blockIdx.x * 64 + (w & 1) * 32;   // this wave's 32-row strip
    int cg = w >> 1;                                 // column half: n-tiles {2cg, 2cg+1}
    int grow_base = rowBase + (lane & 31);
    int arow = (grow_base < M) ? grow_base : (M - 1);
    const float* xr = X + (size_t)arow * GK;
    int kh = (lane >> 5) * 8;                        // 0 or 8
    int bn = lane & 31;

    f32x16 acc[2];
#pragma unroll
    for (int c = 0; c < 2; ++c)
#pragma unroll
        for (int i = 0; i < 16; ++i) acc[c][i] = 0.f;

    stageB(W1T, Bs[0], tid, 0);
    AF a = loadA(xr, kh, false);
    __syncthreads();

    int buf = 0;
    for (int it = 0; it < NKT; ++it) {
        AF an;
        if (it + 1 < NKT) {
            stageB(W1T, Bs[buf ^ 1], tid, 32 * (it + 1));
            an = loadA(xr, kh + 32 * (it + 1), (it + 1) == (NKT - 1));
        }
        bf16x8 af0 = cvt8(a.v0, a.v1);
        bf16x8 af1 = cvt8(a.v2, a.v3);
#pragma unroll
        for (int c = 0; c < 2; ++c) {
            int nt = 2 * cg + c;
            bf16x8 b0 = *(const bf16x8*)&Bs[buf][(32 * nt + bn) * GS + kh];
            acc[c] = __builtin_amdgcn_mfma_f32_32x32x16_bf16(af0, b0, acc[c], 0, 0, 0);
        }
#pragma unroll
        for (int c = 0; c < 2; ++c) {
            int nt = 2 * cg + c;
            bf16x8 b1 = *(const bf16x8*)&Bs[buf][(32 * nt + bn) * GS + 16 + kh];
            acc[c] = __builtin_amdgcn_mfma_f32_32x32x16_bf16(af1, b1, acc[c], 0, 0, 0);
        }
        __syncthreads();
        buf ^= 1;
        a = an;
    }
    // epilogue: C/D layout col=lane&31, row=(reg&3)+8*(reg>>2)+4*(lane>>5)
#pragma unroll
    for (int c = 0; c < 2; ++c) {
        int nt = 2 * cg + c;
#pragma unroll
        for (int reg = 0; reg < 16; ++reg) {
            int rrow = (reg & 3) + 8 * (reg >> 2) + 4 * (lane >> 5);
            int grow = rowBase + rrow;
            int gcol = 32 * nt + (lane & 31);
            if (grow < M) Y[(size_t)grow * GH + gcol] = f2bf(acc[c][reg]);
        }
    }
}

// ---------------- layer-1 aggregate: 128-wide bf16 gather, unroll-16 MLP ----------------

__global__ __launch_bounds__(256) void k_agg1(const unsigned int* __restrict__ H,
                                              unsigned int* __restrict__ O,
                                              const int* __restrict__ row_ptr,
                                              const int2* __restrict__ meta,
                                              const float* __restrict__ dinv,
                                              const float* __restrict__ bias, int n) {
    int wv = threadIdx.x >> 6;
    int lane = threadIdx.x & 63;
    int d = blockIdx.x * 4 + wv;
    if (d >= n) return;
    float dd = dinv[d];
    int beg = row_ptr[d], end = row_ptr[d + 1];
    unsigned int v = H[(size_t)d * 64 + lane];
    float sw = dd * dd;
    float a0 = sw * bflo(v);
    float a1 = sw * bfhi(v);
    int e = beg;
    for (; e + 16 <= end; e += 16) {
        int2 m[16];
        unsigned int u[16];
#pragma unroll
        for (int j = 0; j < 16; ++j) m[j] = meta[e + j];
#pragma unroll
        for (int j = 0; j < 16; ++j) u[j] = H[(size_t)m[j].x * 64 + lane];
#pragma unroll
        for (int j = 0; j < 16; ++j) {
            float wj = __int_as_float(m[j].y);
            a0 = fmaf(wj, bflo(u[j]), a0);
            a1 = fmaf(wj, bfhi(u[j]), a1);
        }
    }
    if (e + 8 <= end) {
        int2 m[8];
        unsigned int u[8];
#pragma unroll
        for (int j = 0; j < 8; ++j) m[j] = meta[e + j];
#pragma unroll
        for (int j = 0; j < 8; ++j) u[j] = H[(size_t)m[j].x * 64 + lane];
#pragma unroll
        for (int j = 0; j < 8; ++j) {
            float wj = __int_as_float(m[j].y);
            a0 = fmaf(wj, bflo(u[j]), a0);
            a1 = fmaf(wj, bfhi(u[j]), a1);
        }
        e += 8;
    }
    if (e + 4 <= end) {
        int2 m[4];
        unsigned int u[4];
#pragma unroll
        for (int j = 0; j < 4; ++j) m[j] = meta[e + j];
#pragma unroll
        for (int j = 0; j < 4; ++j) u[j] = H[(size_t)m[j].x * 64 + lane];
#pragma unroll
        for (int j = 0; j < 4; ++j) {
            float wj = __int_as_float(m[j].y);
            a0 = fmaf(wj, bflo(u[j]), a0);
            a1 = fmaf(wj, bfhi(u[j]), a1);
        }
        e += 4;
    }
    for (; e < end; ++e) {
        int2 m = meta[e];
        unsigned int u = H[(size_t)m.x * 64 + lane];
        float wj = __int_as_float(m.y);
        a0 = fmaf(wj, bflo(u), a0);
        a1 = fmaf(wj, bfhi(u), a1);
    }
    a0 = fmaxf(a0 + bias[2 * lane], 0.f);
    a1 = fmaxf(a1 + bias[2 * lane + 1], 0.f);
    O[(size_t)d * 64 + lane] = (unsigned int)f2bf(a0) | ((unsigned int)f2bf(a1) << 16);
}

// ---------------- layer-2 transform first: G = relu(H1) @ W2, bf16 out, padded to 48 ----------------

__global__ __launch_bounds__(256) void k_gemm2t(const unsigned int* __restrict__ Hb,
                                                const float* __restrict__ W2,
                                                unsigned short* __restrict__ G, int n) {
    __shared__ float ws[128][GCP];
    for (int i = threadIdx.x; i < 128 * GCP; i += 256) {
        int k = i / GCP;
        int c = i - k * GCP;
        ws[k][c] = (c < GC) ? W2[k * GC + c] : 0.f;
    }
    __syncthreads();
    int r0 = blockIdx.x * 512 + threadIdx.x;
    int r1 = r0 + 256;
    bool v0 = r0 < n, v1 = r1 < n;
    float acc0[GCP], acc1[GCP];
#pragma unroll
    for (int c = 0; c < GCP; ++c) { acc0[c] = 0.f; acc1[c] = 0.f; }
    const uint2* h0 = (const uint2*)(Hb + (size_t)(v0 ? r0 : 0) * 64);
    const uint2* h1 = (const uint2*)(Hb + (size_t)(v1 ? r1 : 0) * 64);
    for (int q = 0; q < 32; ++q) {
        uint2 ua = h0[q];
        uint2 ub = h1[q];
        float va[4] = {bflo(ua.x), bfhi(ua.x), bflo(ua.y), bfhi(ua.y)};
        float vb[4] = {bflo(ub.x), bfhi(ub.x), bflo(ub.y), bfhi(ub.y)};
#pragma unroll
        for (int j = 0; j < 4; ++j) {
            int k = 4 * q + j;
#pragma unroll
            for (int cq = 0; cq < GCP / 4; ++cq) {
                float4 wv = *(const float4*)&ws[k][4 * cq];
                acc0[4 * cq + 0] = fmaf(va[j], wv.x, acc0[4 * cq + 0]);
                acc0[4 * cq + 1] = fmaf(va[j], wv.y, acc0[4 * cq + 1]);
                acc0[4 * cq + 2] = fmaf(va[j], wv.z, acc0[4 * cq + 2]);
                acc0[4 * cq + 3] = fmaf(va[j], wv.w, acc0[4 * cq + 3]);
                acc1[4 * cq + 0] = fmaf(vb[j], wv.x, acc1[4 * cq + 0]);
                acc1[4 * cq + 1] = fmaf(vb[j], wv.y, acc1[4 * cq + 1]);
                acc1[4 * cq + 2] = fmaf(vb[j], wv.z, acc1[4 * cq + 2]);
                acc1[4 * cq + 3] = fmaf(vb[j], wv.w, acc1[4 * cq + 3]);
            }
        }
    }
    if (v0) {
#pragma unroll
        for (int c = 0; c < GCP; ++c) G[(size_t)r0 * GCP + c] = f2bf(acc0[c]);
    }
    if (v1) {
#pragma unroll
        for (int c = 0; c < GCP; ++c) G[(size_t)r1 * GCP + c] = f2bf(acc1[c]);
    }
}

// ---------------- layer-2 aggregate at width 48 + bias + log_softmax, write d_out ----------------

__global__ __launch_bounds__(256) void k_agg2(const unsigned short* __restrict__ G,
                                              float* __restrict__ out,
                                              const int* __restrict__ row_ptr,
                                              const int2* __restrict__ meta,
                                              const float* __restrict__ dinv,
                                              const float* __restrict__ b2, int n) {
    int wv = threadIdx.x >> 6;
    int lane = threadIdx.x & 63;
    int gl = (lane < GCP) ? lane : (GCP - 1);
    int d = blockIdx.x * 4 + wv;
    if (d >= n) return;
    float dd = dinv[d];
    int beg = row_ptr[d], end = row_ptr[d + 1];
    float a = dd * dd * bf2f(G[(size_t)d * GCP + gl]);
    int e = beg;
    for (; e + 16 <= end; e += 16) {
        int2 m[16];
        unsigned short u[16];
#pragma unroll
        for (int j = 0; j < 16; ++j) m[j] = meta[e + j];
#pragma unroll
        for (int j = 0; j < 16; ++j) u[j] = G[(size_t)m[j].x * GCP + gl];
#pragma unroll
        for (int j = 0; j < 16; ++j) a = fmaf(__int_as_float(m[j].y), bf2f(u[j]), a);
    }
    if (e + 8 <= end) {
        int2 m[8];
        unsigned short u[8];
#pragma unroll
        for (int j = 0; j < 8; ++j) m[j] = meta[e + j];
#pragma unroll
        for (int j = 0; j < 8; ++j) u[j] = G[(size_t)m[j].x * GCP + gl];
#pragma unroll
        for (int j = 0; j < 8; ++j) a = fmaf(__int_as_float(m[j].y), bf2f(u[j]), a);
        e += 8;
    }
    if (e + 4 <= end) {
        int2 m[4];
        unsigned short u[4];
#pragma unroll
        for (int j = 0; j < 4; ++j) m[j] = meta[e + j];
#pragma unroll
        for (int j = 0; j < 4; ++j) u[j] = G[(size_t)m[j].x * GCP + gl];
#pragma unroll
        for (int j = 0; j < 4; ++j) a = fmaf(__int_as_float(m[j].y), bf2f(u[j]), a);
        e += 4;
    }
    for (; e < end; ++e) {
        int2 m = meta[e];
        a = fmaf(__int_as_float(m.y), bf2f(G[(size_t)m.x * GCP + gl]), a);
    }
    float logit = (lane < GC) ? (a + b2[lane]) : -INFINITY;
    float mx = logit;
#pragma unroll
    for (int off = 32; off; off >>= 1) mx = fmaxf(mx, __shfl_xor(mx, off));
    float ex = (lane < GC) ? __expf(logit - mx) : 0.f;
    float sm = ex;
#pragma unroll
    for (int off = 32; off; off >>= 1) sm += __shfl_xor(sm, off);
    if (lane < GC) out[(size_t)d * GC + lane] = logit - mx - __logf(sm);
}

// ---------------- launch ----------------

static inline size_t alignup256(size_t x) { return (x + 255) & ~(size_t)255; }

extern "C" void kernel_launch(void* const* d_in, const int* in_sizes, int n_in,
                              void* d_out, int out_size, void* d_ws, size_t ws_size,
                              hipStream_t stream) {
    const float* x  = (const float*)d_in[0];
    const int*   ei = (const int*)d_in[1];
    const float* W1 = (const float*)d_in[2];
    const float* b1 = (const float*)d_in[3];
    const float* W2 = (const float*)d_in[4];
    const float* b2 = (const float*)d_in[5];
    float* out = (float*)d_out;

    const int n = in_sizes[0] / GK;   // 100000
    const int E = in_sizes[1] / 2;    // 1600000
    const int* src = ei;
    const int* dst = ei + E;

    char* w = (char*)d_ws;
    char* p;
    p = w; w += alignup256((size_t)n * 4);            float* dinv  = (float*)p;
    p = w; w += alignup256((size_t)n * 4);            int* counts  = (int*)p;
    p = w; w += alignup256((size_t)n * 4);            int* cursor  = (int*)p;
    p = w; w += alignup256((size_t)(n + 1) * 4);      int* row_ptr = (int*)p;
    p = w; w += alignup256(1024 * 4);                 int* bsum    = (int*)p;
    p = w; w += alignup256((size_t)E * 8);            int2* meta   = (int2*)p;
    p = w; w += alignup256((size_t)GH * KPAD * 2);    unsigned short* W1T = (unsigned short*)p;
    p = w; w += alignup256((size_t)n * GH * 2);       unsigned short* bufA = (unsigned short*)p; // bf16 H1
    p = w; w += alignup256((size_t)n * GH * 2);       unsigned short* bufB = (unsigned short*)p; // bf16 relu(agg1)
    p = w; w += alignup256((size_t)n * GCP * 2);      unsigned short* G    = (unsigned short*)p; // bf16 H1relu@W2

    hipMemsetAsync(counts, 0, (size_t)n * 4, stream);

    int gE = (E + 255) / 256;
    int gN = (n + 255) / 256;
    int nb = (n + 1023) / 1024;

    k_hist<<<gE, 256, 0, stream>>>(dst, counts, E);
    k_scan_a<<<nb, 256, 0, stream>>>(counts, row_ptr, bsum, n);
    k_scan_b<<<1, 256, 0, stream>>>(bsum, nb);
    k_scan_c<<<gN, 256, 0, stream>>>(row_ptr, bsum, counts, dinv, cursor, n, E);
    k_fill<<<gE, 256, 0, stream>>>(src, dst, dinv, cursor, meta, E);

    k_prepW1<<<(GH * KPAD + 255) / 256, 256, 0, stream>>>(W1, W1T);
    k_gemm1_mfma<<<(n + 63) / 64, 256, 0, stream>>>(x, W1T, bufA, n);
    k_agg1<<<(n + 3) / 4, 256, 0, stream>>>((const unsigned int*)bufA, (unsigned int*)bufB,
                                            row_ptr, meta, dinv, b1, n);
    k_gemm2t<<<(n + 511) / 512, 256, 0, stream>>>((const unsigned int*)bufB, W2, G, n);
    k_agg2<<<(n + 3) / 4, 256, 0, stream>>>(G, out, row_ptr, meta, dinv, b2, n);
}